// Round 5
// baseline (235.946 us; speedup 1.0000x reference)
//
#include <hip/hip_runtime.h>
#include <cstdint>
#include <cstddef>

#define B_ 4
#define T_ 2048
#define C_ 1024
#define M_ (B_ * T_)   // 8192 rows
#define HALF_ 8
#define W_ 17
#define QKV_STRIDE 3072

typedef unsigned short u16;
typedef _Float16 half8 __attribute__((ext_vector_type(8)));
typedef _Float16 half2_t __attribute__((ext_vector_type(2)));
typedef float f32x16 __attribute__((ext_vector_type(16)));

// ---- async global->LDS, 16B/lane; l is the WAVE-UNIFORM base (m104/m108) ----
__device__ __forceinline__ void gload_lds16(const u16* g, u16* l) {
#if __has_builtin(__builtin_amdgcn_global_load_lds)
    __builtin_amdgcn_global_load_lds(
        (const __attribute__((address_space(1))) void*)g,
        (__attribute__((address_space(3))) void*)l, 16, 0, 0);
#else
    *(uint4*)(l + (threadIdx.x & 63) * 8) = *(const uint4*)g;
#endif
}

__device__ __forceinline__ float dot16(half8 a, half8 b, float acc) {
#if __has_builtin(__builtin_amdgcn_fdot2)
    const half2_t* pa = (const half2_t*)&a;
    const half2_t* pb = (const half2_t*)&b;
#pragma unroll
    for (int e = 0; e < 4; ++e) acc = __builtin_amdgcn_fdot2(pa[e], pb[e], acc, false);
#else
#pragma unroll
    for (int e = 0; e < 8; ++e) acc += (float)a[e] * (float)b[e];
#endif
    return acc;
}

// ---------------- fused prologue: all fp32->fp16 conversions + bias concat ----
__global__ void prologue(const float* __restrict__ x,
                         const float* __restrict__ Wq, const float* __restrict__ Wk,
                         const float* __restrict__ Wv, const float* __restrict__ Wo,
                         const float* __restrict__ bq, const float* __restrict__ bk,
                         const float* __restrict__ bv,
                         u16* __restrict__ xh, u16* __restrict__ wcat,
                         u16* __restrict__ woh, float* __restrict__ bcat) {
    const int blk = blockIdx.x;
    if (blk >= 12288) {   // bias concat
        int i = (blk - 12288) * 256 + threadIdx.x;     // 0..3071
        const float* src = (i < 1024) ? bq : (i < 2048) ? bk : bv;
        bcat[i] = src[i & 1023];
        return;
    }
    const float* src;
    u16* dst;
    int j;
    if (blk < 8192)       { src = x;  dst = xh;   j = blk * 256 + threadIdx.x; }
    else if (blk < 11264) {
        int bb = blk - 8192;
        int sel = bb >> 10;                            // 0,1,2 block-uniform
        src = (sel == 0) ? Wq : (sel == 1) ? Wk : Wv;
        dst = wcat + ((size_t)sel << 20);
        j = (bb - (sel << 10)) * 256 + threadIdx.x;
    } else                { src = Wo; dst = woh;  j = (blk - 11264) * 256 + threadIdx.x; }
    float4 v = ((const float4*)src)[j];
    ushort4 o;
    _Float16 a = (_Float16)v.x; o.x = __builtin_bit_cast(unsigned short, a);
    _Float16 b = (_Float16)v.y; o.y = __builtin_bit_cast(unsigned short, b);
    _Float16 c = (_Float16)v.z; o.z = __builtin_bit_cast(unsigned short, c);
    _Float16 d = (_Float16)v.w; o.w = __builtin_bit_cast(unsigned short, d);
    ((ushort4*)dst)[j] = o;
}

// ---------------- QKV GEMM: 128x128 tile, BK=32, mfma_f32_32x32x16_f16 ----
// (unchanged from R4: 73 us / 644 TF, on the m97-structure curve for this shape)
__global__ __launch_bounds__(256) void gemm_nt_lds(
    const u16* __restrict__ A, const u16* __restrict__ Bw,
    const float* __restrict__ bias, u16* __restrict__ Cout,
    int Ndim, int Kdim)
{
    __shared__ __align__(16) u16 As[128 * 32];
    __shared__ __align__(16) u16 Bs[128 * 32];

    const int tid  = threadIdx.x;
    const int lane = tid & 63;
    const int wave = tid >> 6;
    const int m0 = blockIdx.y * 128;
    const int n0 = blockIdx.x * 128;
    const int wm = (wave >> 1) * 64;
    const int wn = (wave & 1) * 64;

    const int srow = wave * 32 + (lane >> 2);
    const int kc = ((lane & 3) ^ ((lane >> 3) & 3)) * 8;
    const u16* Ap = A  + (size_t)(m0 + srow) * Kdim + kc;
    const u16* Bp = Bw + (size_t)(n0 + srow) * Kdim + kc;
    const size_t skip16 = (size_t)16 * Kdim;
    u16* AsW = As + wave * 1024;
    u16* BsW = Bs + wave * 1024;

    f32x16 acc[2][2];
#pragma unroll
    for (int i = 0; i < 2; ++i)
#pragma unroll
        for (int j = 0; j < 2; ++j)
#pragma unroll
            for (int r = 0; r < 16; ++r) acc[i][j][r] = 0.f;

    const int rr = lane & 31;
    const int hi = lane >> 5;
    const int sw = (lane >> 1) & 3;

    for (int k0 = 0; k0 < Kdim; k0 += 32) {
        __syncthreads();
        gload_lds16(Ap + k0,          AsW);
        gload_lds16(Ap + k0 + skip16, AsW + 512);
        gload_lds16(Bp + k0,          BsW);
        gload_lds16(Bp + k0 + skip16, BsW + 512);
        __syncthreads();

#pragma unroll
        for (int kk = 0; kk < 2; ++kk) {
            const int slot = ((kk * 2 + hi) ^ sw) * 8;
            half8 af[2], bf[2];
#pragma unroll
            for (int i = 0; i < 2; ++i)
                af[i] = *(const half8*)&As[(wm + i * 32 + rr) * 32 + slot];
#pragma unroll
            for (int j = 0; j < 2; ++j)
                bf[j] = *(const half8*)&Bs[(wn + j * 32 + rr) * 32 + slot];
#pragma unroll
            for (int i = 0; i < 2; ++i)
#pragma unroll
                for (int j = 0; j < 2; ++j)
                    acc[i][j] = __builtin_amdgcn_mfma_f32_32x32x16_f16(af[i], bf[j], acc[i][j], 0, 0, 0);
        }
    }

    // C/D: col = lane&31, row = (reg&3) + 8*(reg>>2) + 4*(lane>>5)  [m74/m101]
#pragma unroll
    for (int i = 0; i < 2; ++i) {
#pragma unroll
        for (int j = 0; j < 2; ++j) {
            const int col = n0 + wn + j * 32 + (lane & 31);
            const float bv = bias[col];
#pragma unroll
            for (int reg = 0; reg < 16; ++reg) {
                const int row = m0 + wm + i * 32 + (reg & 3) + 8 * (reg >> 2) + 4 * (lane >> 5);
                _Float16 h = (_Float16)(acc[i][j][reg] + bv);
                Cout[(size_t)row * Ndim + col] = __builtin_bit_cast(unsigned short, h);
            }
        }
    }
}

// ---------------- Wo GEMM: 128x64 tile, BK=32 -> 1024 blocks = 4/CU ----
// Fixes R4's 2-blocks/CU latency exposure (Wo ran at QKV's 73us with 1/3 FLOPs).
// 4 waves x (64x32 via 2x1 of 32x32). fp32 output + bias.
__global__ __launch_bounds__(256) void gemm_nt_64(
    const u16* __restrict__ A, const u16* __restrict__ Bw,
    const float* __restrict__ bias, float* __restrict__ Cout,
    int Ndim, int Kdim)
{
    __shared__ __align__(16) u16 As[128 * 32];
    __shared__ __align__(16) u16 Bs[64 * 32];

    const int tid  = threadIdx.x;
    const int lane = tid & 63;
    const int wave = tid >> 6;
    const int m0 = blockIdx.y * 128;
    const int n0 = blockIdx.x * 64;
    const int wm = (wave >> 1) * 64;
    const int wn = (wave & 1) * 32;

    // A staging: wave w rows [w*32, w*32+32), 2 instrs (16-row skip)
    const int sArow = wave * 32 + (lane >> 2);
    // B staging: wave w rows [w*16, w*16+16), 1 instr
    const int sBrow = wave * 16 + (lane >> 2);
    const int kc = ((lane & 3) ^ ((lane >> 3) & 3)) * 8;   // same parity swizzle
    const u16* Ap = A  + (size_t)(m0 + sArow) * Kdim + kc;
    const u16* Bp = Bw + (size_t)(n0 + sBrow) * Kdim + kc;
    const size_t skip16 = (size_t)16 * Kdim;
    u16* AsW = As + wave * 1024;
    u16* BsW = Bs + wave * 512;

    f32x16 acc[2];
#pragma unroll
    for (int i = 0; i < 2; ++i)
#pragma unroll
        for (int r = 0; r < 16; ++r) acc[i][r] = 0.f;

    const int rr = lane & 31;
    const int hi = lane >> 5;
    const int sw = (lane >> 1) & 3;

    for (int k0 = 0; k0 < Kdim; k0 += 32) {
        __syncthreads();
        gload_lds16(Ap + k0,          AsW);
        gload_lds16(Ap + k0 + skip16, AsW + 512);
        gload_lds16(Bp + k0,          BsW);
        __syncthreads();

#pragma unroll
        for (int kk = 0; kk < 2; ++kk) {
            const int slot = ((kk * 2 + hi) ^ sw) * 8;
            half8 bf = *(const half8*)&Bs[(wn + rr) * 32 + slot];
#pragma unroll
            for (int i = 0; i < 2; ++i) {
                half8 af = *(const half8*)&As[(wm + i * 32 + rr) * 32 + slot];
                acc[i] = __builtin_amdgcn_mfma_f32_32x32x16_f16(af, bf, acc[i], 0, 0, 0);
            }
        }
    }

    const int col = n0 + wn + (lane & 31);
    const float bv = bias[col];
#pragma unroll
    for (int i = 0; i < 2; ++i) {
#pragma unroll
        for (int reg = 0; reg < 16; ++reg) {
            const int row = m0 + wm + i * 32 + (reg & 3) + 8 * (reg >> 2) + 4 * (lane >> 5);
            Cout[(size_t)row * Ndim + col] = acc[i][reg] + bv;
        }
    }
}

// ---------------- windowed attention: one wave per token, branchless ----
// (reverted to R2 structure: 8192 waves = 32/CU for latency hiding)
__global__ __launch_bounds__(256) void attn_local(
    const u16* __restrict__ qkv, u16* __restrict__ ctx)
{
    const int wid  = blockIdx.x * 4 + (threadIdx.x >> 6);
    const int lane = threadIdx.x & 63;
    const int b = wid >> 11;
    const int t = wid & (T_ - 1);
    const int base = b * T_;
    const size_t qrow = (size_t)(base + t) * QKV_STRIDE;
    const int c0 = lane * 8;

    half8 q0 = *(const half8*)(qkv + qrow + c0);
    half8 q1 = *(const half8*)(qkv + qrow + 512 + c0);

    float s[W_];
#pragma unroll
    for (int o = 0; o < W_; ++o) {
        int j = t - HALF_ + o;
        int jc = min(max(j, 0), T_ - 1);
        const size_t kb = (size_t)(base + jc) * QKV_STRIDE + 1024;
        half8 k0v = *(const half8*)(qkv + kb + c0);
        half8 k1v = *(const half8*)(qkv + kb + 512 + c0);
        float d = dot16(q1, k1v, dot16(q0, k0v, 0.f));
#pragma unroll
        for (int off = 32; off > 0; off >>= 1)
            d += __shfl_xor(d, off);
        s[o] = (j == jc) ? d * 0.03125f : -3.0e38f;
    }

    float mx = s[0];
#pragma unroll
    for (int o = 1; o < W_; ++o) mx = fmaxf(mx, s[o]);
    float den = 0.f;
#pragma unroll
    for (int o = 0; o < W_; ++o) den += __expf(s[o] - mx);
    const float inv = 1.f / den;

    float acc0[8], acc1[8];
#pragma unroll
    for (int e = 0; e < 8; ++e) { acc0[e] = 0.f; acc1[e] = 0.f; }
#pragma unroll
    for (int o = 0; o < W_; ++o) {
        int j = t - HALF_ + o;
        int jc = min(max(j, 0), T_ - 1);
        const float wt = __expf(s[o] - mx) * inv;
        const size_t vb_ = (size_t)(base + jc) * QKV_STRIDE + 2048;
        half8 v0 = *(const half8*)(qkv + vb_ + c0);
        half8 v1 = *(const half8*)(qkv + vb_ + 512 + c0);
#pragma unroll
        for (int e = 0; e < 8; ++e) {
            acc0[e] += wt * (float)v0[e];
            acc1[e] += wt * (float)v1[e];
        }
    }

    const size_t crow = (size_t)(base + t) * C_;
    half8 o0, o1;
#pragma unroll
    for (int e = 0; e < 8; ++e) { o0[e] = (_Float16)acc0[e]; o1[e] = (_Float16)acc1[e]; }
    *(half8*)(ctx + crow + c0) = o0;
    *(half8*)(ctx + crow + 512 + c0) = o1;
}

// ---------------- host launch ----------------
extern "C" void kernel_launch(void* const* d_in, const int* in_sizes, int n_in,
                              void* d_out, int out_size, void* d_ws, size_t ws_size,
                              hipStream_t stream) {
    const float* x  = (const float*)d_in[0];
    const float* Wq = (const float*)d_in[1];
    const float* bq = (const float*)d_in[2];
    const float* Wk = (const float*)d_in[3];
    const float* bk = (const float*)d_in[4];
    const float* Wv = (const float*)d_in[5];
    const float* bv = (const float*)d_in[6];
    const float* Wo = (const float*)d_in[7];
    const float* bo = (const float*)d_in[8];
    float* out = (float*)d_out;

    u16* xh   = (u16*)d_ws;                         // 8M halves
    u16* wcat = xh   + (size_t)M_ * C_;             // 3M  (Wq;Wk;Wv)
    u16* woh  = wcat + (size_t)3 * C_ * C_;         // 1M
    u16* qkvh = woh  + (size_t)C_ * C_;             // 24M (M x 3072)
    u16* ctxh = qkvh + (size_t)M_ * QKV_STRIDE;     // 8M
    float* bcat = (float*)(ctxh + (size_t)M_ * C_); // 3072 floats

    prologue<<<12300, 256, 0, stream>>>(x, Wq, Wk, Wv, Wo, bq, bk, bv,
                                        xh, wcat, woh, bcat);

    dim3 gqkv(QKV_STRIDE / 128, M_ / 128);   // (24, 64) = 1536 blocks
    gemm_nt_lds<<<gqkv, 256, 0, stream>>>(xh, wcat, bcat, qkvh, QKV_STRIDE, C_);

    attn_local<<<M_ / 4, 256, 0, stream>>>(qkvh, ctxh);   // 2048 blocks

    dim3 go(C_ / 64, M_ / 128);              // (16, 64) = 1024 blocks
    gemm_nt_64<<<go, 256, 0, stream>>>(ctxh, woh, bo, out, C_, C_);
}